// Round 10
// baseline (223.589 us; speedup 1.0000x reference)
//
#include <hip/hip_runtime.h>

#define B_ 8
#define N_ 4096
#define K_ 32
#define C_ 64
#define CIN_ 67
#define R2_ 0.0225f

#define PTS 4     // points per block-iteration
#define ITERS 4   // iterations per block (16 points per block)

typedef short short8v __attribute__((ext_vector_type(8)));
typedef short short4v __attribute__((ext_vector_type(4)));
typedef float floatx4 __attribute__((ext_vector_type(4)));

// Hardware bf16 convert (RNE): compiler packs pairs into v_cvt_pk_bf16_f32.
__device__ __forceinline__ short f2bf(float x) {
    return (short)__builtin_bit_cast(unsigned short, (__bf16)x);
}

// 16-lane sum via DPP (VALU pipe, not LDS): xor1, xor2, half-mirror, mirror.
template <int CTRL>
__device__ __forceinline__ float dpp_add(float x) {
    const int m = __builtin_amdgcn_update_dpp(0, __float_as_int(x), CTRL, 0xF, 0xF, false);
    return x + __int_as_float(m);
}
__device__ __forceinline__ float row16_sum(float x) {
    x = dpp_add<0xB1>(x);    // quad_perm(1,0,3,2)  : xor1
    x = dpp_add<0x4E>(x);    // quad_perm(2,3,0,1)  : xor2
    x = dpp_add<0x141>(x);   // row_half_mirror     : 8-groups combine
    x = dpp_add<0x140>(x);   // row_mirror          : halves combine
    return x;
}

// ---------------------------------------------------------------------------
// Prep: f[b][c][n] -> ftb[b][n][c] (bf16), p passthrough -> out, and packed
// p4[b][n] = (x,y,z,|p|^2). sq uses the validated contract-off expression.
// ---------------------------------------------------------------------------
__global__ __launch_bounds__(256) void prep_kernel(
    const float* __restrict__ p, const float* __restrict__ f,
    unsigned short* __restrict__ ftb, float4* __restrict__ p4,
    float* __restrict__ pout)
{
#pragma clang fp contract(off)
    __shared__ short tile[64 * 72];
    const int t = threadIdx.x;
    const int b = blockIdx.x >> 6;
    const int n0 = (blockIdx.x & 63) * 64;
    const int nn4 = t & 15, ch = t >> 4;
    for (int cc = 0; cc < 4; ++cc) {
        const int c = cc * 16 + ch;
        const float4 v = *(const float4*)&f[((size_t)(b * 64 + c)) * N_ + n0 + nn4 * 4];
        tile[(nn4 * 4 + 0) * 72 + c] = f2bf(v.x);
        tile[(nn4 * 4 + 1) * 72 + c] = f2bf(v.y);
        tile[(nn4 * 4 + 2) * 72 + c] = f2bf(v.z);
        tile[(nn4 * 4 + 3) * 72 + c] = f2bf(v.w);
    }
    if (t < 48) {   // p passthrough (192 floats per block, 16B-aligned)
        const size_t base = ((size_t)(b * N_ + n0)) * 3;
        ((float4*)(pout + base))[t] = ((const float4*)(p + base))[t];
    }
    if (t < 64) {   // packed p4
        const int n = n0 + t;
        const float x = p[((size_t)(b * N_ + n)) * 3 + 0];
        const float y = p[((size_t)(b * N_ + n)) * 3 + 1];
        const float z = p[((size_t)(b * N_ + n)) * 3 + 2];
        const float sq = (x * x + y * y) + z * z;
        p4[(size_t)b * N_ + n] = make_float4(x, y, z, sq);
    }
    __syncthreads();
    const int nn = t >> 2, cb = (t & 3) * 16;
    uint4* dst = (uint4*)&ftb[((size_t)(b * N_ + n0 + nn)) * 64 + cb];
    const uint4* src = (const uint4*)&tile[nn * 72 + cb];
    dst[0] = src[0];
    dst[1] = src[1];
}

// ---------------------------------------------------------------------------
// Ball query, 4 queries per wave (one shared candidate load per chunk),
// standalone for full occupancy (8 waves/SIMD hides L2 latency).
// Proven round-0 version (1-query/wave variant regressed: 4x load traffic).
// ---------------------------------------------------------------------------
__global__ __launch_bounds__(256) void ball_query_kernel(
    const float4* __restrict__ p4, unsigned short* __restrict__ idx)
{
#pragma clang fp contract(off)
    const int lane = threadIdx.x & 63;
    const int wid = (blockIdx.x * blockDim.x + threadIdx.x) >> 6;
    const int q0 = wid * 4;
    const int b = q0 >> 12;
    const float4* pb = p4 + (size_t)b * N_;

    float4 Q[4];
    #pragma unroll
    for (int q = 0; q < 4; ++q)
        Q[q] = pb[(q0 + q) & (N_ - 1)];
    int count[4] = {0, 0, 0, 0};
    int first[4] = {-1, -1, -1, -1};
    for (int base = 0; base < N_; base += 64) {
        const float4 A = pb[base + lane];
        unsigned long long m[4];
        bool w[4];
        #pragma unroll
        for (int q = 0; q < 4; ++q) {
            const float d2 = (Q[q].w + A.w)
                - 2.0f * ((Q[q].x * A.x + Q[q].y * A.y) + Q[q].z * A.z);
            w[q] = (d2 <= R2_);
            m[q] = __ballot(w[q]);
        }
        const unsigned long long below = (1ull << lane) - 1ull;
        #pragma unroll
        for (int q = 0; q < 4; ++q) {
            if (m[q]) {
                if (first[q] < 0) first[q] = base + __builtin_ctzll(m[q]);
                if (w[q]) {
                    const int pos = count[q] + __popcll(m[q] & below);
                    if (pos < K_)
                        idx[(size_t)(q0 + q) * K_ + pos] = (unsigned short)(base + lane);
                }
                count[q] += __popcll(m[q]);
            }
        }
        if (count[0] >= K_ && count[1] >= K_ && count[2] >= K_ && count[3] >= K_)
            break;
    }
    #pragma unroll
    for (int q = 0; q < 4; ++q)
        for (int pos = count[q] + lane; pos < K_; pos += 64)
            idx[(size_t)(q0 + q) * K_ + pos] = (unsigned short)first[q];
}

// ---------------------------------------------------------------------------
// Fused MFMA kernel — ONE barrier per iteration via double-buffered fj/y1.
// bar(n), mid-iteration, is the ONLY loop barrier: it publishes y1[cur]
// (cross-wave, conv2 needs all channels) and fj/dp[nxt] (next phase A).
// Waves decouple across the softmax<->phaseA boundary: a fast wave's phase
// A(n+1) writes y1[nxt]/reads fj[nxt] while a slow wave still reads y1[cur]
// in conv2(n) — disjoint buffers, no race (audit at bottom).
// Layout: R2-validated compact LDS (fj rows 64 shorts + dp-split + XOR
// swizzle (row&7)<<3 on 16B granules; y1/fbuf 64-stride swizzled). 77824 B
// -> 2 blocks/CU (matches the effective residency counters already show).
// HW f2bf (R8), batched FFN (R9), T14 gather pipeline (R7) retained.
// Launch bounds: plain (256) — caps cause scratch spill (R2/R3); body must
// stay <=128 VGPR for 4 waves/SIMD.
// ---------------------------------------------------------------------------
__global__ __launch_bounds__(256) void lpa_mfma_kernel(
    const float4* __restrict__ p4, const float* __restrict__ f,
    const unsigned short* __restrict__ ftb,
    const float* __restrict__ w_attn, const float* __restrict__ b_attn,
    const float* __restrict__ w1, const float* __restrict__ b1,
    const float* __restrict__ w2, const float* __restrict__ b2,
    const float* __restrict__ wf1, const float* __restrict__ bf1,
    const float* __restrict__ wf2, const float* __restrict__ bf2,
    const unsigned short* __restrict__ idx, float* __restrict__ out)
{
    __shared__ __align__(16) short s_fj[2][128 * 64];   // 32768 B (swizzled)
    __shared__ __align__(16) short s_dp[2][128 * 8];    // 4096 B
    __shared__ __align__(16) short s_y1[2][128 * 64];   // 32768 B (swizzled)
    __shared__ __align__(16) short s_fbuf[2 * 16 * 64]; // 4096 B (swizzled)
    __shared__ float s_vec[16 * 64];                    // 4096 B
    short* s_vecbf = s_fbuf;                            // total 77824 B
    short* s_hbf   = s_fbuf + 16 * 64;

    const int t = threadIdx.x;
    const int lane = t & 63;
    const int mb = t >> 6;
    const int l15 = lane & 15;
    const int quad = lane >> 4;

    // ---- weight A-fragments in registers (once per block) ----
    short8v wa_f[3], w1_f[3], w2_f[2], wf1_f[2], wf2_f[2];
    {
        const int cm = mb * 16 + l15;
        #pragma unroll
        for (int ks = 0; ks < 3; ++ks) {
            short8v a, bq;
            #pragma unroll
            for (int j = 0; j < 8; ++j) {
                const int ip = ks * 32 + quad * 8 + j;   // permuted i'
                float va = 0.0f, vb = 0.0f;
                if (ip < 64)      { va = w_attn[cm * CIN_ + ip + 3];  vb = w1[cm * CIN_ + ip + 3]; }
                else if (ip < 67) { va = w_attn[cm * CIN_ + ip - 64]; vb = w1[cm * CIN_ + ip - 64]; }
                a[j] = f2bf(va); bq[j] = f2bf(vb);
            }
            wa_f[ks] = a; w1_f[ks] = bq;
        }
        #pragma unroll
        for (int ks = 0; ks < 2; ++ks) {
            short8v a, bq, cq;
            #pragma unroll
            for (int j = 0; j < 8; ++j) {
                const int kk = ks * 32 + quad * 8 + j;
                a[j]  = f2bf(w2[cm * 64 + kk]);
                bq[j] = f2bf(wf1[cm * 64 + kk]);
                cq[j] = f2bf(wf2[cm * 64 + kk]);
            }
            w2_f[ks] = a; wf1_f[ks] = bq; wf2_f[ks] = cq;
        }
    }

    const int crow = mb * 16 + quad * 4;          // C/D row base (channel)
    const float4 bav  = *(const float4*)&b_attn[crow];
    const float4 b1v  = *(const float4*)&b1[crow];
    const float4 b2v  = *(const float4*)&b2[crow];
    const float4 bf1v = *(const float4*)&bf1[crow];
    const float4 bf2v = *(const float4*)&bf2[crow];

    const int pt00 = blockIdx.x * (PTS * ITERS);
    const int bb = pt00 >> 12;
    const float4* pb = p4 + (size_t)bb * N_;

    const int col = t >> 1, h = t & 1;   // gather geometry, fixed per thread
    const int gsw = (col & 7) << 3;      // gather-side swizzle

    // ---- prologue: gather iter 0 into buffer 0 ----
    {
        const int j = idx[(size_t)pt00 * K_ + col];
        const uint4* src = (const uint4*)&ftb[((size_t)(bb * N_ + j)) * 64 + h * 32];
        const int rb = col * 64;
        *(uint4*)&s_fj[0][rb + ((h * 32 + 0)  ^ gsw)] = src[0];
        *(uint4*)&s_fj[0][rb + ((h * 32 + 8)  ^ gsw)] = src[1];
        *(uint4*)&s_fj[0][rb + ((h * 32 + 16) ^ gsw)] = src[2];
        *(uint4*)&s_fj[0][rb + ((h * 32 + 24) ^ gsw)] = src[3];
        if (h) {
            const int n = (pt00 + (col >> 5)) & (N_ - 1);
            const float4 Pj = pb[j];
            const float4 Pn = pb[n];
            short8v dp = {};
            dp[0] = f2bf(Pj.x - Pn.x);
            dp[1] = f2bf(Pj.y - Pn.y);
            dp[2] = f2bf(Pj.z - Pn.z);
            *(short8v*)&s_dp[0][col * 8] = dp;
        }
    }
    __syncthreads();   // b0: iter-0 fj ready

    for (int itn = 0; itn < ITERS; ++itn) {
        const int pt0 = pt00 + itn * PTS;
        const int cur = itn & 1, nxt = cur ^ 1;

        // ---- issue next-iter gather loads (fly under phase A) ----
        const bool pf = (itn + 1 < ITERS);
        uint4 g0, g1, g2, g3;
        float4 Pjn, Pnn;
        if (pf) {
            const int jn = idx[(size_t)(pt0 + PTS) * K_ + col];
            const uint4* src = (const uint4*)&ftb[((size_t)(bb * N_ + jn)) * 64 + h * 32];
            g0 = src[0]; g1 = src[1]; g2 = src[2]; g3 = src[3];
            Pjn = pb[jn];
            Pnn = pb[(pt0 + PTS + (col >> 5)) & (N_ - 1)];
        }

        // ---- attn + conv1 MFMAs (shared B-frags); y1 -> LDS[cur] ----
        floatx4 accA[8];
        #pragma unroll
        for (int nt = 0; nt < 8; ++nt) {
            const int row = nt * 16 + l15;
            const int sw = (l15 & 7) << 3;     // row&7 == l15&7
            const short* bp = &s_fj[cur][row * 64];
            const short8v fb0 = *(const short8v*)(bp + ((quad * 8) ^ sw));
            const short8v fb1 = *(const short8v*)(bp + ((32 + quad * 8) ^ sw));
            const short8v dpv = *(const short8v*)&s_dp[cur][row * 8];
            short8v fb2 = {};
            if (quad == 0) fb2 = dpv;          // quads 1-3: zero tail (R2-validated)
            floatx4 a = {0.f, 0.f, 0.f, 0.f};
            a = __builtin_amdgcn_mfma_f32_16x16x32_bf16(wa_f[0], fb0, a, 0, 0, 0);
            a = __builtin_amdgcn_mfma_f32_16x16x32_bf16(wa_f[1], fb1, a, 0, 0, 0);
            a = __builtin_amdgcn_mfma_f32_16x16x32_bf16(wa_f[2], fb2, a, 0, 0, 0);
            accA[nt] = a;
            floatx4 y = {0.f, 0.f, 0.f, 0.f};
            y = __builtin_amdgcn_mfma_f32_16x16x32_bf16(w1_f[0], fb0, y, 0, 0, 0);
            y = __builtin_amdgcn_mfma_f32_16x16x32_bf16(w1_f[1], fb1, y, 0, 0, 0);
            y = __builtin_amdgcn_mfma_f32_16x16x32_bf16(w1_f[2], fb2, y, 0, 0, 0);
            short4v yp;
            yp[0] = f2bf(fmaxf(y[0] + b1v.x, 0.f));
            yp[1] = f2bf(fmaxf(y[1] + b1v.y, 0.f));
            yp[2] = f2bf(fmaxf(y[2] + b1v.z, 0.f));
            yp[3] = f2bf(fmaxf(y[3] + b1v.w, 0.f));
            *(short4v*)&s_y1[cur][row * 64 + (crow ^ sw)] = yp;
        }

        // ---- write prefetched gather into the ALT buffers (pre-barrier) ----
        if (pf) {
            const int rb = col * 64;
            *(uint4*)&s_fj[nxt][rb + ((h * 32 + 0)  ^ gsw)] = g0;
            *(uint4*)&s_fj[nxt][rb + ((h * 32 + 8)  ^ gsw)] = g1;
            *(uint4*)&s_fj[nxt][rb + ((h * 32 + 16) ^ gsw)] = g2;
            *(uint4*)&s_fj[nxt][rb + ((h * 32 + 24) ^ gsw)] = g3;
            if (h) {
                short8v dp = {};
                dp[0] = f2bf(Pjn.x - Pnn.x);
                dp[1] = f2bf(Pjn.y - Pnn.y);
                dp[2] = f2bf(Pjn.z - Pnn.z);
                *(short8v*)&s_dp[nxt][col * 8] = dp;
            }
        }
        __syncthreads();   // bar(n): publishes y1[cur] + fj/dp[nxt]

        // ---- fres: 4 aligned float4 loads; nb0 = within-batch index ----
        const int nb0 = pt0 & (N_ - 1);   // multiple of 4; nb0+3 <= 4095
        float4 f4r[4];
        #pragma unroll
        for (int r = 0; r < 4; ++r)
            f4r[r] = *(const float4*)&f[((size_t)(bb * 64 + crow + r)) * N_ + nb0];

        // ---- conv2 MFMAs interleaved with softmax, per point ----
        #pragma unroll
        for (int pi = 0; pi < PTS; ++pi) {
            floatx4 xx0, xx1;
            {
                const int row = (2 * pi) * 16 + l15;
                const int sw = (l15 & 7) << 3;
                const short* bp = &s_y1[cur][row * 64];
                const short8v yb0 = *(const short8v*)(bp + ((quad * 8) ^ sw));
                const short8v yb1 = *(const short8v*)(bp + ((32 + quad * 8) ^ sw));
                floatx4 x = {0.f, 0.f, 0.f, 0.f};
                x = __builtin_amdgcn_mfma_f32_16x16x32_bf16(w2_f[0], yb0, x, 0, 0, 0);
                x = __builtin_amdgcn_mfma_f32_16x16x32_bf16(w2_f[1], yb1, x, 0, 0, 0);
                xx0 = x;
            }
            {
                const int row = (2 * pi + 1) * 16 + l15;
                const int sw = (l15 & 7) << 3;
                const short* bp = &s_y1[cur][row * 64];
                const short8v yb0 = *(const short8v*)(bp + ((quad * 8) ^ sw));
                const short8v yb1 = *(const short8v*)(bp + ((32 + quad * 8) ^ sw));
                floatx4 x = {0.f, 0.f, 0.f, 0.f};
                x = __builtin_amdgcn_mfma_f32_16x16x32_bf16(w2_f[0], yb0, x, 0, 0, 0);
                x = __builtin_amdgcn_mfma_f32_16x16x32_bf16(w2_f[1], yb1, x, 0, 0, 0);
                xx1 = x;
            }
            float fo[4];
            #pragma unroll
            for (int r = 0; r < 4; ++r) {
                const float ba = (r == 0) ? bav.x : (r == 1) ? bav.y : (r == 2) ? bav.z : bav.w;
                const float bx = (r == 0) ? b2v.x : (r == 1) ? b2v.y : (r == 2) ? b2v.z : b2v.w;
                const float e0 = __expf(accA[2 * pi][r] + ba);
                const float e1 = __expf(accA[2 * pi + 1][r] + ba);
                const float t01 = e0 + e1;
                const float se = row16_sum(t01);
                const float sw_ = row16_sum(e0 * xx0[r] + e1 * xx1[r] + t01 * bx);
                const float fres = (pi == 0) ? f4r[r].x : (pi == 1) ? f4r[r].y
                                 : (pi == 2) ? f4r[r].z : f4r[r].w;
                fo[r] = fmaxf(sw_ * __builtin_amdgcn_rcpf(se) + fres, 0.f);
            }
            if (l15 == 0) {
                const int prow = itn * PTS + pi;        // point row 0..15
                *(float4*)&s_vec[prow * 64 + crow] = make_float4(fo[0], fo[1], fo[2], fo[3]);
                short4v fb;
                fb[0] = f2bf(fo[0]); fb[1] = f2bf(fo[1]);
                fb[2] = f2bf(fo[2]); fb[3] = f2bf(fo[3]);
                *(short4v*)&s_vecbf[prow * 64 + (crow ^ ((prow & 7) << 3))] = fb;
            }
        }
        // no trailing barrier: next phase A uses fj[nxt]/writes y1[nxt] —
        // disjoint from this iteration's y1[cur] reads. See audit below.
    }
    __syncthreads();   // publish vecbf rows (cross-wave channels)

    // ---- BATCHED FFN layer 1: M=16 (wave ch), K=64 (ch), N=16 (points) ----
    {
        const int sw = (l15 & 7) << 3;
        const short8v vb0 = *(const short8v*)&s_vecbf[l15 * 64 + ((quad * 8) ^ sw)];
        const short8v vb1 = *(const short8v*)&s_vecbf[l15 * 64 + ((32 + quad * 8) ^ sw)];
        floatx4 d = {0.f, 0.f, 0.f, 0.f};
        d = __builtin_amdgcn_mfma_f32_16x16x32_bf16(wf1_f[0], vb0, d, 0, 0, 0);
        d = __builtin_amdgcn_mfma_f32_16x16x32_bf16(wf1_f[1], vb1, d, 0, 0, 0);
        short4v hb;
        hb[0] = f2bf(fmaxf(d[0] + bf1v.x, 0.f));
        hb[1] = f2bf(fmaxf(d[1] + bf1v.y, 0.f));
        hb[2] = f2bf(fmaxf(d[2] + bf1v.z, 0.f));
        hb[3] = f2bf(fmaxf(d[3] + bf1v.w, 0.f));
        *(short4v*)&s_hbf[l15 * 64 + (crow ^ sw)] = hb;
    }
    __syncthreads();   // h ready (cross-wave channels)

    // ---- BATCHED FFN layer 2 + residual + relu, store all 16 points ----
    {
        const int sw = (l15 & 7) << 3;
        const short8v hb0 = *(const short8v*)&s_hbf[l15 * 64 + ((quad * 8) ^ sw)];
        const short8v hb1 = *(const short8v*)&s_hbf[l15 * 64 + ((32 + quad * 8) ^ sw)];
        floatx4 d = {0.f, 0.f, 0.f, 0.f};
        d = __builtin_amdgcn_mfma_f32_16x16x32_bf16(wf2_f[0], hb0, d, 0, 0, 0);
        d = __builtin_amdgcn_mfma_f32_16x16x32_bf16(wf2_f[1], hb1, d, 0, 0, 0);
        const int n = (pt00 + l15) & (N_ - 1);       // block spans one batch
        out[((size_t)(bb * 64 + crow + 0)) * N_ + n] =
            fmaxf(d[0] + bf2v.x + s_vec[l15 * 64 + crow + 0], 0.f);
        out[((size_t)(bb * 64 + crow + 1)) * N_ + n] =
            fmaxf(d[1] + bf2v.y + s_vec[l15 * 64 + crow + 1], 0.f);
        out[((size_t)(bb * 64 + crow + 2)) * N_ + n] =
            fmaxf(d[2] + bf2v.z + s_vec[l15 * 64 + crow + 2], 0.f);
        out[((size_t)(bb * 64 + crow + 3)) * N_ + n] =
            fmaxf(d[3] + bf2v.w + s_vec[l15 * 64 + crow + 3], 0.f);
    }
    // hazard audit (1-barrier loop): y1[cur] writes (phase A(n), pre-bar(n))
    // vs conv2(n) reads (post-bar(n)) — ordered by bar(n). phase A(n+1)
    // writes y1[nxt] / reads fj[nxt] while slow waves read y1[cur] in
    // conv2(n): disjoint buffers. fj/dp[nxt] writes (pre-bar(n), all waves)
    // vs phase A(n+1) reads (post-bar(n)) — ordered by bar(n). Iter n+1's
    // gather write targets fj[cur-of-n]: its readers (phase A(n)) finished
    // pre-bar(n), and the write is post-bar(n) (it sits pre-bar(n+1)) —
    // ordered. vecbf/s_vec rows are per-(itn,pi) disjoint, read post-loop
    // after the publish barrier; s_hbf written once, read post-FFN-barrier;
    // s_vec store-reads are wave-local channels.
}

extern "C" void kernel_launch(void* const* d_in, const int* in_sizes, int n_in,
                              void* d_out, int out_size, void* d_ws, size_t ws_size,
                              hipStream_t stream)
{
    const float* p      = (const float*)d_in[0];
    const float* f      = (const float*)d_in[1];
    const float* w_attn = (const float*)d_in[2];
    const float* b_attn = (const float*)d_in[3];
    const float* w1     = (const float*)d_in[4];
    const float* b1     = (const float*)d_in[5];
    const float* w2     = (const float*)d_in[6];
    const float* b2     = (const float*)d_in[7];
    const float* wf1    = (const float*)d_in[8];
    const float* bf1    = (const float*)d_in[9];
    const float* wf2    = (const float*)d_in[10];
    const float* bf2    = (const float*)d_in[11];
    float* out = (float*)d_out;

    unsigned short* idx = (unsigned short*)d_ws;                             // 2 MB
    unsigned short* ftb = (unsigned short*)((char*)d_ws + 2u * 1024 * 1024); // 4 MB
    float4* p4          = (float4*)((char*)d_ws + 6u * 1024 * 1024);         // 512 KB

    prep_kernel<<<B_ * (N_ / 64), 256, 0, stream>>>(p, f, ftb, p4, out);
    // 32768 queries / 4 per wave / 4 waves per block = 2048 blocks
    ball_query_kernel<<<(B_ * N_) / 16, 256, 0, stream>>>(p4, idx);
    lpa_mfma_kernel<<<(B_ * N_) / (PTS * ITERS), 256, 0, stream>>>(
        p4, f, ftb, w_attn, b_attn, w1, b1, w2, b2, wf1, bf1, wf2, bf2,
        idx, out + (size_t)B_ * N_ * 3);
}

// Round 11
// 222.929 us; speedup vs baseline: 1.0030x; 1.0030x over previous
//
#include <hip/hip_runtime.h>

#define B_ 8
#define N_ 4096
#define K_ 32
#define C_ 64
#define CIN_ 67
#define R2_ 0.0225f

#define SFJ 104   // s_fj row stride in shorts (208 B: 16B-aligned, 2-way banks)
#define SY1 72    // s_y1 row stride in shorts (144 B)
#define SFB 72    // s_vecbf / s_hbf row stride in shorts
#define PTS 4     // points per block-iteration
#define ITERS 4   // iterations per block (16 points per block)

typedef short short8v __attribute__((ext_vector_type(8)));
typedef short short4v __attribute__((ext_vector_type(4)));
typedef float floatx4 __attribute__((ext_vector_type(4)));

// Hardware bf16 convert (RNE): compiler packs pairs into v_cvt_pk_bf16_f32.
__device__ __forceinline__ short f2bf(float x) {
    return (short)__builtin_bit_cast(unsigned short, (__bf16)x);
}

// 16-lane sum via DPP (VALU pipe, not LDS): xor1, xor2, half-mirror, mirror.
template <int CTRL>
__device__ __forceinline__ float dpp_add(float x) {
    const int m = __builtin_amdgcn_update_dpp(0, __float_as_int(x), CTRL, 0xF, 0xF, false);
    return x + __int_as_float(m);
}
__device__ __forceinline__ float row16_sum(float x) {
    x = dpp_add<0xB1>(x);    // quad_perm(1,0,3,2)  : xor1
    x = dpp_add<0x4E>(x);    // quad_perm(2,3,0,1)  : xor2
    x = dpp_add<0x141>(x);   // row_half_mirror     : 8-groups combine
    x = dpp_add<0x140>(x);   // row_mirror          : halves combine
    return x;
}

// ---------------------------------------------------------------------------
// Prep: f[b][c][n] -> ftb[b][n][c] (bf16), p passthrough -> out, and packed
// p4[b][n] = (x,y,z,|p|^2). sq uses the validated contract-off expression.
// ---------------------------------------------------------------------------
__global__ __launch_bounds__(256) void prep_kernel(
    const float* __restrict__ p, const float* __restrict__ f,
    unsigned short* __restrict__ ftb, float4* __restrict__ p4,
    float* __restrict__ pout)
{
#pragma clang fp contract(off)
    __shared__ short tile[64 * 72];
    const int t = threadIdx.x;
    const int b = blockIdx.x >> 6;
    const int n0 = (blockIdx.x & 63) * 64;
    const int nn4 = t & 15, ch = t >> 4;
    for (int cc = 0; cc < 4; ++cc) {
        const int c = cc * 16 + ch;
        const float4 v = *(const float4*)&f[((size_t)(b * 64 + c)) * N_ + n0 + nn4 * 4];
        tile[(nn4 * 4 + 0) * 72 + c] = f2bf(v.x);
        tile[(nn4 * 4 + 1) * 72 + c] = f2bf(v.y);
        tile[(nn4 * 4 + 2) * 72 + c] = f2bf(v.z);
        tile[(nn4 * 4 + 3) * 72 + c] = f2bf(v.w);
    }
    if (t < 48) {   // p passthrough (192 floats per block, 16B-aligned)
        const size_t base = ((size_t)(b * N_ + n0)) * 3;
        ((float4*)(pout + base))[t] = ((const float4*)(p + base))[t];
    }
    if (t < 64) {   // packed p4
        const int n = n0 + t;
        const float x = p[((size_t)(b * N_ + n)) * 3 + 0];
        const float y = p[((size_t)(b * N_ + n)) * 3 + 1];
        const float z = p[((size_t)(b * N_ + n)) * 3 + 2];
        const float sq = (x * x + y * y) + z * z;
        p4[(size_t)b * N_ + n] = make_float4(x, y, z, sq);
    }
    __syncthreads();
    const int nn = t >> 2, cb = (t & 3) * 16;
    uint4* dst = (uint4*)&ftb[((size_t)(b * N_ + n0 + nn)) * 64 + cb];
    const uint4* src = (const uint4*)&tile[nn * 72 + cb];
    dst[0] = src[0];
    dst[1] = src[1];
}

// ---------------------------------------------------------------------------
// Ball query, 4 queries per wave (one shared candidate load per chunk),
// standalone for full occupancy (8 waves/SIMD hides L2 latency).
// Proven round-0 version (1-query/wave variant regressed: 4x load traffic).
// ---------------------------------------------------------------------------
__global__ __launch_bounds__(256) void ball_query_kernel(
    const float4* __restrict__ p4, unsigned short* __restrict__ idx)
{
#pragma clang fp contract(off)
    const int lane = threadIdx.x & 63;
    const int wid = (blockIdx.x * blockDim.x + threadIdx.x) >> 6;
    const int q0 = wid * 4;
    const int b = q0 >> 12;
    const float4* pb = p4 + (size_t)b * N_;

    float4 Q[4];
    #pragma unroll
    for (int q = 0; q < 4; ++q)
        Q[q] = pb[(q0 + q) & (N_ - 1)];
    int count[4] = {0, 0, 0, 0};
    int first[4] = {-1, -1, -1, -1};
    for (int base = 0; base < N_; base += 64) {
        const float4 A = pb[base + lane];
        unsigned long long m[4];
        bool w[4];
        #pragma unroll
        for (int q = 0; q < 4; ++q) {
            const float d2 = (Q[q].w + A.w)
                - 2.0f * ((Q[q].x * A.x + Q[q].y * A.y) + Q[q].z * A.z);
            w[q] = (d2 <= R2_);
            m[q] = __ballot(w[q]);
        }
        const unsigned long long below = (1ull << lane) - 1ull;
        #pragma unroll
        for (int q = 0; q < 4; ++q) {
            if (m[q]) {
                if (first[q] < 0) first[q] = base + __builtin_ctzll(m[q]);
                if (w[q]) {
                    const int pos = count[q] + __popcll(m[q] & below);
                    if (pos < K_)
                        idx[(size_t)(q0 + q) * K_ + pos] = (unsigned short)(base + lane);
                }
                count[q] += __popcll(m[q]);
            }
        }
        if (count[0] >= K_ && count[1] >= K_ && count[2] >= K_ && count[3] >= K_)
            break;
    }
    #pragma unroll
    for (int q = 0; q < 4; ++q)
        for (int pos = count[q] + lane; pos < K_; pos += 64)
            idx[(size_t)(q0 + q) * K_ + pos] = (unsigned short)first[q];
}

// ---------------------------------------------------------------------------
// Fused MFMA kernel — session-best configuration (R9, 94.5 us):
//   R0 LDS layout (SFJ=104: natural 2-way banks, zero swizzle VALU)
//   + T14 gather pipeline, bar1 deleted (R7)
//   + hardware f2bf / v_cvt_pk_bf16_f32 (R8)
//   + batched single-shot FFN over all 16 points (R9).
// Lever ledger (measured): occupancy up = null (R5); conflicts down 5x =
// null (R5/R10); barriers below 2/iter = net-negative, swizzle VALU cost
// exceeds decoupling gain (R10); VALU reduction = ~0.5 us/us (R8/R9).
// Launch bounds: plain (256) — min-waves caps cause scratch spill (R2: 64
// VGPR/520 MB, R3: 84 VGPR/240 MB). Body compiles to ~104 VGPR <= 128 ->
// 4 waves/SIMD step. LDS 53760 -> 3 blocks/CU.
// ---------------------------------------------------------------------------
__global__ __launch_bounds__(256) void lpa_mfma_kernel(
    const float4* __restrict__ p4, const float* __restrict__ f,
    const unsigned short* __restrict__ ftb,
    const float* __restrict__ w_attn, const float* __restrict__ b_attn,
    const float* __restrict__ w1, const float* __restrict__ b1,
    const float* __restrict__ w2, const float* __restrict__ b2,
    const float* __restrict__ wf1, const float* __restrict__ bf1,
    const float* __restrict__ wf2, const float* __restrict__ bf2,
    const unsigned short* __restrict__ idx, float* __restrict__ out)
{
    __shared__ __align__(16) short s_fj[128 * SFJ];      // 26624 B
    __shared__ __align__(16) short s_y1[128 * SY1];      // 18432 B
    __shared__ __align__(16) short s_fbuf[2 * 16 * SFB]; // 4608 B
    __shared__ float s_vec[PTS * ITERS * 64];            // 4096 B
    short* s_vecbf = s_fbuf;
    short* s_hbf   = s_fbuf + 16 * SFB;

    const int t = threadIdx.x;
    const int lane = t & 63;
    const int mb = t >> 6;
    const int l15 = lane & 15;
    const int quad = lane >> 4;

    // ---- weight A-fragments in registers (once per block) ----
    short8v wa_f[3], w1_f[3], w2_f[2], wf1_f[2], wf2_f[2];
    {
        const int cm = mb * 16 + l15;
        #pragma unroll
        for (int ks = 0; ks < 3; ++ks) {
            short8v a, bq;
            #pragma unroll
            for (int j = 0; j < 8; ++j) {
                const int ip = ks * 32 + quad * 8 + j;   // permuted i'
                float va = 0.0f, vb = 0.0f;
                if (ip < 64)      { va = w_attn[cm * CIN_ + ip + 3];  vb = w1[cm * CIN_ + ip + 3]; }
                else if (ip < 67) { va = w_attn[cm * CIN_ + ip - 64]; vb = w1[cm * CIN_ + ip - 64]; }
                a[j] = f2bf(va); bq[j] = f2bf(vb);
            }
            wa_f[ks] = a; w1_f[ks] = bq;
        }
        #pragma unroll
        for (int ks = 0; ks < 2; ++ks) {
            short8v a, bq, cq;
            #pragma unroll
            for (int j = 0; j < 8; ++j) {
                const int kk = ks * 32 + quad * 8 + j;
                a[j]  = f2bf(w2[cm * 64 + kk]);
                bq[j] = f2bf(wf1[cm * 64 + kk]);
                cq[j] = f2bf(wf2[cm * 64 + kk]);
            }
            w2_f[ks] = a; wf1_f[ks] = bq; wf2_f[ks] = cq;
        }
    }

    const int crow = mb * 16 + quad * 4;          // C/D row base (channel)
    const float4 bav  = *(const float4*)&b_attn[crow];
    const float4 b1v  = *(const float4*)&b1[crow];
    const float4 b2v  = *(const float4*)&b2[crow];
    const float4 bf1v = *(const float4*)&bf1[crow];
    const float4 bf2v = *(const float4*)&bf2[crow];

    // zero fj pad region i'=[72,104) and the ffn staging buffers (defensive
    // once-per-block; all 16 rows are fully written in the batched scheme)
    for (int e = t; e < 512; e += 256) {
        const int col = e >> 2, c4 = e & 3;
        *(uint4*)&s_fj[col * SFJ + 72 + c4 * 8] = make_uint4(0u, 0u, 0u, 0u);
    }
    for (int e = t; e < 1152; e += 256) ((unsigned*)s_fbuf)[e] = 0u;

    const int pt00 = blockIdx.x * (PTS * ITERS);
    const int bb = pt00 >> 12;
    const float4* pb = p4 + (size_t)bb * N_;

    const int col = t >> 1, h = t & 1;   // gather geometry, fixed per thread

    // ---- prologue: gather iter 0 directly to LDS ----
    {
        const int j = idx[(size_t)pt00 * K_ + col];
        const uint4* src = (const uint4*)&ftb[((size_t)(bb * N_ + j)) * 64 + h * 32];
        uint4* dst = (uint4*)&s_fj[col * SFJ + h * 32];
        dst[0] = src[0]; dst[1] = src[1]; dst[2] = src[2]; dst[3] = src[3];
        if (h) {
            const int n = (pt00 + (col >> 5)) & (N_ - 1);
            const float4 Pj = pb[j];
            const float4 Pn = pb[n];
            short8v dp = {};
            dp[0] = f2bf(Pj.x - Pn.x);
            dp[1] = f2bf(Pj.y - Pn.y);
            dp[2] = f2bf(Pj.z - Pn.z);
            *(short8v*)&s_fj[col * SFJ + 64] = dp;
        }
    }
    __syncthreads();   // b0: iter-0 fj ready

    for (int itn = 0; itn < ITERS; ++itn) {
        const int pt0 = pt00 + itn * PTS;

        // ---- issue next-iter gather loads (fly under phase A) ----
        const bool pf = (itn + 1 < ITERS);
        uint4 g0, g1, g2, g3;
        float4 Pjn, Pnn;
        if (pf) {
            const int jn = idx[(size_t)(pt0 + PTS) * K_ + col];
            const uint4* src = (const uint4*)&ftb[((size_t)(bb * N_ + jn)) * 64 + h * 32];
            g0 = src[0]; g1 = src[1]; g2 = src[2]; g3 = src[3];
            Pjn = pb[jn];
            Pnn = pb[(pt0 + PTS + (col >> 5)) & (N_ - 1)];
        }

        // ---- attn + conv1 MFMAs (shared B-frags); y1 -> LDS ----
        floatx4 accA[8];
        #pragma unroll
        for (int nt = 0; nt < 8; ++nt) {
            const short* bp = &s_fj[(nt * 16 + l15) * SFJ + quad * 8];
            const short8v fb0 = *(const short8v*)(bp);
            const short8v fb1 = *(const short8v*)(bp + 32);
            const short8v fb2 = *(const short8v*)(bp + 64);
            floatx4 a = {0.f, 0.f, 0.f, 0.f};
            a = __builtin_amdgcn_mfma_f32_16x16x32_bf16(wa_f[0], fb0, a, 0, 0, 0);
            a = __builtin_amdgcn_mfma_f32_16x16x32_bf16(wa_f[1], fb1, a, 0, 0, 0);
            a = __builtin_amdgcn_mfma_f32_16x16x32_bf16(wa_f[2], fb2, a, 0, 0, 0);
            accA[nt] = a;
            floatx4 y = {0.f, 0.f, 0.f, 0.f};
            y = __builtin_amdgcn_mfma_f32_16x16x32_bf16(w1_f[0], fb0, y, 0, 0, 0);
            y = __builtin_amdgcn_mfma_f32_16x16x32_bf16(w1_f[1], fb1, y, 0, 0, 0);
            y = __builtin_amdgcn_mfma_f32_16x16x32_bf16(w1_f[2], fb2, y, 0, 0, 0);
            short4v yp;
            yp[0] = f2bf(fmaxf(y[0] + b1v.x, 0.f));
            yp[1] = f2bf(fmaxf(y[1] + b1v.y, 0.f));
            yp[2] = f2bf(fmaxf(y[2] + b1v.z, 0.f));
            yp[3] = f2bf(fmaxf(y[3] + b1v.w, 0.f));
            *(short4v*)&s_y1[(nt * 16 + l15) * SY1 + crow] = yp;
        }
        __syncthreads();   // bar2: y1 ready; all s_fj reads of this iter done

        // ---- write prefetched gather for iter n+1 (safe: past bar2) ----
        if (pf) {
            uint4* dst = (uint4*)&s_fj[col * SFJ + h * 32];
            dst[0] = g0; dst[1] = g1; dst[2] = g2; dst[3] = g3;
            if (h) {
                short8v dp = {};
                dp[0] = f2bf(Pjn.x - Pnn.x);
                dp[1] = f2bf(Pjn.y - Pnn.y);
                dp[2] = f2bf(Pjn.z - Pnn.z);
                *(short8v*)&s_fj[col * SFJ + 64] = dp;
            }
        }

        // ---- fres: 4 aligned float4 loads; nb0 = within-batch index ----
        const int nb0 = pt0 & (N_ - 1);   // multiple of 4; nb0+3 <= 4095
        float4 f4r[4];
        #pragma unroll
        for (int r = 0; r < 4; ++r)
            f4r[r] = *(const float4*)&f[((size_t)(bb * 64 + crow + r)) * N_ + nb0];

        // ---- conv2 MFMAs interleaved with softmax, per point ----
        #pragma unroll
        for (int pi = 0; pi < PTS; ++pi) {
            floatx4 xx0, xx1;
            {
                const short* bp = &s_y1[((2 * pi) * 16 + l15) * SY1 + quad * 8];
                const short8v yb0 = *(const short8v*)(bp);
                const short8v yb1 = *(const short8v*)(bp + 32);
                floatx4 x = {0.f, 0.f, 0.f, 0.f};
                x = __builtin_amdgcn_mfma_f32_16x16x32_bf16(w2_f[0], yb0, x, 0, 0, 0);
                x = __builtin_amdgcn_mfma_f32_16x16x32_bf16(w2_f[1], yb1, x, 0, 0, 0);
                xx0 = x;
            }
            {
                const short* bp = &s_y1[((2 * pi + 1) * 16 + l15) * SY1 + quad * 8];
                const short8v yb0 = *(const short8v*)(bp);
                const short8v yb1 = *(const short8v*)(bp + 32);
                floatx4 x = {0.f, 0.f, 0.f, 0.f};
                x = __builtin_amdgcn_mfma_f32_16x16x32_bf16(w2_f[0], yb0, x, 0, 0, 0);
                x = __builtin_amdgcn_mfma_f32_16x16x32_bf16(w2_f[1], yb1, x, 0, 0, 0);
                xx1 = x;
            }
            float fo[4];
            #pragma unroll
            for (int r = 0; r < 4; ++r) {
                const float ba = (r == 0) ? bav.x : (r == 1) ? bav.y : (r == 2) ? bav.z : bav.w;
                const float bx = (r == 0) ? b2v.x : (r == 1) ? b2v.y : (r == 2) ? b2v.z : b2v.w;
                const float e0 = __expf(accA[2 * pi][r] + ba);
                const float e1 = __expf(accA[2 * pi + 1][r] + ba);
                const float t01 = e0 + e1;
                const float se = row16_sum(t01);
                const float sw = row16_sum(e0 * xx0[r] + e1 * xx1[r] + t01 * bx);
                const float fres = (pi == 0) ? f4r[r].x : (pi == 1) ? f4r[r].y
                                 : (pi == 2) ? f4r[r].z : f4r[r].w;
                fo[r] = fmaxf(sw * __builtin_amdgcn_rcpf(se) + fres, 0.f);
            }
            if (l15 == 0) {
                const int prow = itn * PTS + pi;        // point row 0..15
                *(float4*)&s_vec[prow * 64 + crow] = make_float4(fo[0], fo[1], fo[2], fo[3]);
                short4v fb;
                fb[0] = f2bf(fo[0]); fb[1] = f2bf(fo[1]);
                fb[2] = f2bf(fo[2]); fb[3] = f2bf(fo[3]);
                *(short4v*)&s_vecbf[prow * SFB + crow] = fb;
            }
        }
        __syncthreads();   // bar_end: publishes vecbf rows + s_fj gather;
                           // protects s_y1 from next iter's phase-A writes
    }

    // ---- BATCHED FFN layer 1: M=16 (wave ch), K=64 (ch), N=16 (points) ----
    {
        const short8v vb0 = *(const short8v*)&s_vecbf[l15 * SFB + quad * 8];
        const short8v vb1 = *(const short8v*)&s_vecbf[l15 * SFB + 32 + quad * 8];
        floatx4 d = {0.f, 0.f, 0.f, 0.f};
        d = __builtin_amdgcn_mfma_f32_16x16x32_bf16(wf1_f[0], vb0, d, 0, 0, 0);
        d = __builtin_amdgcn_mfma_f32_16x16x32_bf16(wf1_f[1], vb1, d, 0, 0, 0);
        short4v hb;
        hb[0] = f2bf(fmaxf(d[0] + bf1v.x, 0.f));
        hb[1] = f2bf(fmaxf(d[1] + bf1v.y, 0.f));
        hb[2] = f2bf(fmaxf(d[2] + bf1v.z, 0.f));
        hb[3] = f2bf(fmaxf(d[3] + bf1v.w, 0.f));
        *(short4v*)&s_hbf[l15 * SFB + crow] = hb;   // all 16 rows real
    }
    __syncthreads();   // h ready (cross-wave channels)

    // ---- BATCHED FFN layer 2 + residual + relu, store all 16 points ----
    {
        const short8v hb0 = *(const short8v*)&s_hbf[l15 * SFB + quad * 8];
        const short8v hb1 = *(const short8v*)&s_hbf[l15 * SFB + 32 + quad * 8];
        floatx4 d = {0.f, 0.f, 0.f, 0.f};
        d = __builtin_amdgcn_mfma_f32_16x16x32_bf16(wf2_f[0], hb0, d, 0, 0, 0);
        d = __builtin_amdgcn_mfma_f32_16x16x32_bf16(wf2_f[1], hb1, d, 0, 0, 0);
        const int n = (pt00 + l15) & (N_ - 1);       // block spans one batch
        out[((size_t)(bb * 64 + crow + 0)) * N_ + n] =
            fmaxf(d[0] + bf2v.x + s_vec[l15 * 64 + crow + 0], 0.f);
        out[((size_t)(bb * 64 + crow + 1)) * N_ + n] =
            fmaxf(d[1] + bf2v.y + s_vec[l15 * 64 + crow + 1], 0.f);
        out[((size_t)(bb * 64 + crow + 2)) * N_ + n] =
            fmaxf(d[2] + bf2v.z + s_vec[l15 * 64 + crow + 2], 0.f);
        out[((size_t)(bb * 64 + crow + 3)) * N_ + n] =
            fmaxf(d[3] + bf2v.w + s_vec[l15 * 64 + crow + 3], 0.f);
    }
    // hazard audit (batched): per iter, s_fj gather-writes (post-bar2(n)) vs
    // phase-A(n+1) reads separated by bar_end(n); s_y1 phase-A(n+1) writes vs
    // conv2(n) reads separated by bar_end(n); vecbf/s_vec rows written pre-
    // bar_end(n), read only after bar_end(3) (FFN1) / FFN-barrier (store) —
    // rows are per-(itn,pi) disjoint so no overwrite hazard; s_hbf written
    // once (FFN1), read after the FFN barrier.
}

extern "C" void kernel_launch(void* const* d_in, const int* in_sizes, int n_in,
                              void* d_out, int out_size, void* d_ws, size_t ws_size,
                              hipStream_t stream)
{
    const float* p      = (const float*)d_in[0];
    const float* f      = (const float*)d_in[1];
    const float* w_attn = (const float*)d_in[2];
    const float* b_attn = (const float*)d_in[3];
    const float* w1     = (const float*)d_in[4];
    const float* b1     = (const float*)d_in[5];
    const float* w2     = (const float*)d_in[6];
    const float* b2     = (const float*)d_in[7];
    const float* wf1    = (const float*)d_in[8];
    const float* bf1    = (const float*)d_in[9];
    const float* wf2    = (const float*)d_in[10];
    const float* bf2    = (const float*)d_in[11];
    float* out = (float*)d_out;

    unsigned short* idx = (unsigned short*)d_ws;                             // 2 MB
    unsigned short* ftb = (unsigned short*)((char*)d_ws + 2u * 1024 * 1024); // 4 MB
    float4* p4          = (float4*)((char*)d_ws + 6u * 1024 * 1024);         // 512 KB

    prep_kernel<<<B_ * (N_ / 64), 256, 0, stream>>>(p, f, ftb, p4, out);
    // 32768 queries / 4 per wave / 4 waves per block = 2048 blocks
    ball_query_kernel<<<(B_ * N_) / 16, 256, 0, stream>>>(p4, idx);
    lpa_mfma_kernel<<<(B_ * N_) / (PTS * ITERS), 256, 0, stream>>>(
        p4, f, ftb, w_attn, b_attn, w1, b1, w2, b2, wf1, bf1, wf2, bf2,
        idx, out + (size_t)B_ * N_ * 3);
}

// Round 12
// 217.246 us; speedup vs baseline: 1.0292x; 1.0262x over previous
//
#include <hip/hip_runtime.h>

#define B_ 8
#define N_ 4096
#define K_ 32
#define C_ 64
#define CIN_ 67
#define R2_ 0.0225f

#define SFJ 104   // s_fj row stride in shorts (208 B: 16B-aligned, 2-way banks)
#define SY1 72    // s_y1 row stride in shorts (144 B)
#define SFB 72    // s_vecbf / s_hbf row stride in shorts
#define PTS 4     // points per block-iteration
#define ITERS 4   // iterations per block (16 points per block)

typedef short short8v __attribute__((ext_vector_type(8)));
typedef short short4v __attribute__((ext_vector_type(4)));
typedef float floatx4 __attribute__((ext_vector_type(4)));

// Hardware bf16 convert (RNE): compiler packs pairs into v_cvt_pk_bf16_f32.
__device__ __forceinline__ short f2bf(float x) {
    return (short)__builtin_bit_cast(unsigned short, (__bf16)x);
}

// 16-lane sum via DPP (VALU pipe, not LDS): xor1, xor2, half-mirror, mirror.
template <int CTRL>
__device__ __forceinline__ float dpp_add(float x) {
    const int m = __builtin_amdgcn_update_dpp(0, __float_as_int(x), CTRL, 0xF, 0xF, false);
    return x + __int_as_float(m);
}
__device__ __forceinline__ float row16_sum(float x) {
    x = dpp_add<0xB1>(x);    // quad_perm(1,0,3,2)  : xor1
    x = dpp_add<0x4E>(x);    // quad_perm(2,3,0,1)  : xor2
    x = dpp_add<0x141>(x);   // row_half_mirror     : 8-groups combine
    x = dpp_add<0x140>(x);   // row_mirror          : halves combine
    return x;
}

// ---------------------------------------------------------------------------
// Prep: f[b][c][n] -> ftb[b][n][c] (bf16), p passthrough -> out, and packed
// p4[b][n] = (x,y,z,|p|^2). sq uses the validated contract-off expression.
// ---------------------------------------------------------------------------
__global__ __launch_bounds__(256) void prep_kernel(
    const float* __restrict__ p, const float* __restrict__ f,
    unsigned short* __restrict__ ftb, float4* __restrict__ p4,
    float* __restrict__ pout)
{
#pragma clang fp contract(off)
    __shared__ short tile[64 * 72];
    const int t = threadIdx.x;
    const int b = blockIdx.x >> 6;
    const int n0 = (blockIdx.x & 63) * 64;
    const int nn4 = t & 15, ch = t >> 4;
    for (int cc = 0; cc < 4; ++cc) {
        const int c = cc * 16 + ch;
        const float4 v = *(const float4*)&f[((size_t)(b * 64 + c)) * N_ + n0 + nn4 * 4];
        tile[(nn4 * 4 + 0) * 72 + c] = f2bf(v.x);
        tile[(nn4 * 4 + 1) * 72 + c] = f2bf(v.y);
        tile[(nn4 * 4 + 2) * 72 + c] = f2bf(v.z);
        tile[(nn4 * 4 + 3) * 72 + c] = f2bf(v.w);
    }
    if (t < 48) {   // p passthrough (192 floats per block, 16B-aligned)
        const size_t base = ((size_t)(b * N_ + n0)) * 3;
        ((float4*)(pout + base))[t] = ((const float4*)(p + base))[t];
    }
    if (t < 64) {   // packed p4
        const int n = n0 + t;
        const float x = p[((size_t)(b * N_ + n)) * 3 + 0];
        const float y = p[((size_t)(b * N_ + n)) * 3 + 1];
        const float z = p[((size_t)(b * N_ + n)) * 3 + 2];
        const float sq = (x * x + y * y) + z * z;
        p4[(size_t)b * N_ + n] = make_float4(x, y, z, sq);
    }
    __syncthreads();
    const int nn = t >> 2, cb = (t & 3) * 16;
    uint4* dst = (uint4*)&ftb[((size_t)(b * N_ + n0 + nn)) * 64 + cb];
    const uint4* src = (const uint4*)&tile[nn * 72 + cb];
    dst[0] = src[0];
    dst[1] = src[1];
}

// ---------------------------------------------------------------------------
// Ball query, 4 queries per wave (one shared candidate load per chunk) +
// UNIFORM per-query skip once count[q] >= K (this round). count[q] is
// wave-uniform (sum of ballot popcounts) -> the skip is a scalar branch,
// no divergence. Bit-identical outputs: after count>=K no store can pass
// pos<K, first is already set, and the padding loop only runs for queries
// with final count<K — which are never skipped (they never reach K).
// Saves the dead ~13-op pipeline per finished query per remaining chunk
// (~28% of inner work: avg per-query exit ~44 chunks vs wave max ~61).
// ---------------------------------------------------------------------------
__global__ __launch_bounds__(256) void ball_query_kernel(
    const float4* __restrict__ p4, unsigned short* __restrict__ idx)
{
#pragma clang fp contract(off)
    const int lane = threadIdx.x & 63;
    const int wid = (blockIdx.x * blockDim.x + threadIdx.x) >> 6;
    const int q0 = wid * 4;
    const int b = q0 >> 12;
    const float4* pb = p4 + (size_t)b * N_;

    float4 Q[4];
    #pragma unroll
    for (int q = 0; q < 4; ++q)
        Q[q] = pb[(q0 + q) & (N_ - 1)];
    int count[4] = {0, 0, 0, 0};
    int first[4] = {-1, -1, -1, -1};
    const unsigned long long below = (1ull << lane) - 1ull;
    for (int base = 0; base < N_; base += 64) {
        const float4 A = pb[base + lane];
        #pragma unroll
        for (int q = 0; q < 4; ++q) {
            if (count[q] >= K_) continue;          // uniform: query finished
            const float d2 = (Q[q].w + A.w)
                - 2.0f * ((Q[q].x * A.x + Q[q].y * A.y) + Q[q].z * A.z);
            const bool w = (d2 <= R2_);
            const unsigned long long m = __ballot(w);
            if (m) {
                if (first[q] < 0) first[q] = base + __builtin_ctzll(m);
                if (w) {
                    const int pos = count[q] + __popcll(m & below);
                    if (pos < K_)
                        idx[(size_t)(q0 + q) * K_ + pos] = (unsigned short)(base + lane);
                }
                count[q] += __popcll(m);
            }
        }
        if (count[0] >= K_ && count[1] >= K_ && count[2] >= K_ && count[3] >= K_)
            break;
    }
    #pragma unroll
    for (int q = 0; q < 4; ++q)
        for (int pos = count[q] + lane; pos < K_; pos += 64)
            idx[(size_t)(q0 + q) * K_ + pos] = (unsigned short)first[q];
}

// ---------------------------------------------------------------------------
// Fused MFMA kernel — session-best configuration (R9, ~94-100 us band):
//   R0 LDS layout (SFJ=104: natural 2-way banks, zero swizzle VALU)
//   + T14 gather pipeline, bar1 deleted (R7)
//   + hardware f2bf / v_cvt_pk_bf16_f32 (R8)
//   + batched single-shot FFN over all 16 points (R9).
// Lever ledger (measured): occupancy up = null (R5); conflicts down 5x =
// null (R5/R10); barriers below 2/iter = net-negative, swizzle VALU cost
// exceeds decoupling gain (R10); VALU reduction = ~0.5 us/us (R8/R9).
// Launch bounds: plain (256) — min-waves caps cause scratch spill (R2: 64
// VGPR/520 MB, R3: 84 VGPR/240 MB). Body compiles to 104 VGPR <= 128 ->
// 4 waves/SIMD step. LDS 53760 -> 3 blocks/CU.
// ---------------------------------------------------------------------------
__global__ __launch_bounds__(256) void lpa_mfma_kernel(
    const float4* __restrict__ p4, const float* __restrict__ f,
    const unsigned short* __restrict__ ftb,
    const float* __restrict__ w_attn, const float* __restrict__ b_attn,
    const float* __restrict__ w1, const float* __restrict__ b1,
    const float* __restrict__ w2, const float* __restrict__ b2,
    const float* __restrict__ wf1, const float* __restrict__ bf1,
    const float* __restrict__ wf2, const float* __restrict__ bf2,
    const unsigned short* __restrict__ idx, float* __restrict__ out)
{
    __shared__ __align__(16) short s_fj[128 * SFJ];      // 26624 B
    __shared__ __align__(16) short s_y1[128 * SY1];      // 18432 B
    __shared__ __align__(16) short s_fbuf[2 * 16 * SFB]; // 4608 B
    __shared__ float s_vec[PTS * ITERS * 64];            // 4096 B
    short* s_vecbf = s_fbuf;
    short* s_hbf   = s_fbuf + 16 * SFB;

    const int t = threadIdx.x;
    const int lane = t & 63;
    const int mb = t >> 6;
    const int l15 = lane & 15;
    const int quad = lane >> 4;

    // ---- weight A-fragments in registers (once per block) ----
    short8v wa_f[3], w1_f[3], w2_f[2], wf1_f[2], wf2_f[2];
    {
        const int cm = mb * 16 + l15;
        #pragma unroll
        for (int ks = 0; ks < 3; ++ks) {
            short8v a, bq;
            #pragma unroll
            for (int j = 0; j < 8; ++j) {
                const int ip = ks * 32 + quad * 8 + j;   // permuted i'
                float va = 0.0f, vb = 0.0f;
                if (ip < 64)      { va = w_attn[cm * CIN_ + ip + 3];  vb = w1[cm * CIN_ + ip + 3]; }
                else if (ip < 67) { va = w_attn[cm * CIN_ + ip - 64]; vb = w1[cm * CIN_ + ip - 64]; }
                a[j] = f2bf(va); bq[j] = f2bf(vb);
            }
            wa_f[ks] = a; w1_f[ks] = bq;
        }
        #pragma unroll
        for (int ks = 0; ks < 2; ++ks) {
            short8v a, bq, cq;
            #pragma unroll
            for (int j = 0; j < 8; ++j) {
                const int kk = ks * 32 + quad * 8 + j;
                a[j]  = f2bf(w2[cm * 64 + kk]);
                bq[j] = f2bf(wf1[cm * 64 + kk]);
                cq[j] = f2bf(wf2[cm * 64 + kk]);
            }
            w2_f[ks] = a; wf1_f[ks] = bq; wf2_f[ks] = cq;
        }
    }

    const int crow = mb * 16 + quad * 4;          // C/D row base (channel)
    const float4 bav  = *(const float4*)&b_attn[crow];
    const float4 b1v  = *(const float4*)&b1[crow];
    const float4 b2v  = *(const float4*)&b2[crow];
    const float4 bf1v = *(const float4*)&bf1[crow];
    const float4 bf2v = *(const float4*)&bf2[crow];

    // zero fj pad region i'=[72,104) and the ffn staging buffers (defensive
    // once-per-block; all 16 rows are fully written in the batched scheme)
    for (int e = t; e < 512; e += 256) {
        const int col = e >> 2, c4 = e & 3;
        *(uint4*)&s_fj[col * SFJ + 72 + c4 * 8] = make_uint4(0u, 0u, 0u, 0u);
    }
    for (int e = t; e < 1152; e += 256) ((unsigned*)s_fbuf)[e] = 0u;

    const int pt00 = blockIdx.x * (PTS * ITERS);
    const int bb = pt00 >> 12;
    const float4* pb = p4 + (size_t)bb * N_;

    const int col = t >> 1, h = t & 1;   // gather geometry, fixed per thread

    // ---- prologue: gather iter 0 directly to LDS ----
    {
        const int j = idx[(size_t)pt00 * K_ + col];
        const uint4* src = (const uint4*)&ftb[((size_t)(bb * N_ + j)) * 64 + h * 32];
        uint4* dst = (uint4*)&s_fj[col * SFJ + h * 32];
        dst[0] = src[0]; dst[1] = src[1]; dst[2] = src[2]; dst[3] = src[3];
        if (h) {
            const int n = (pt00 + (col >> 5)) & (N_ - 1);
            const float4 Pj = pb[j];
            const float4 Pn = pb[n];
            short8v dp = {};
            dp[0] = f2bf(Pj.x - Pn.x);
            dp[1] = f2bf(Pj.y - Pn.y);
            dp[2] = f2bf(Pj.z - Pn.z);
            *(short8v*)&s_fj[col * SFJ + 64] = dp;
        }
    }
    __syncthreads();   // b0: iter-0 fj ready

    for (int itn = 0; itn < ITERS; ++itn) {
        const int pt0 = pt00 + itn * PTS;

        // ---- issue next-iter gather loads (fly under phase A) ----
        const bool pf = (itn + 1 < ITERS);
        uint4 g0, g1, g2, g3;
        float4 Pjn, Pnn;
        if (pf) {
            const int jn = idx[(size_t)(pt0 + PTS) * K_ + col];
            const uint4* src = (const uint4*)&ftb[((size_t)(bb * N_ + jn)) * 64 + h * 32];
            g0 = src[0]; g1 = src[1]; g2 = src[2]; g3 = src[3];
            Pjn = pb[jn];
            Pnn = pb[(pt0 + PTS + (col >> 5)) & (N_ - 1)];
        }

        // ---- attn + conv1 MFMAs (shared B-frags); y1 -> LDS ----
        floatx4 accA[8];
        #pragma unroll
        for (int nt = 0; nt < 8; ++nt) {
            const short* bp = &s_fj[(nt * 16 + l15) * SFJ + quad * 8];
            const short8v fb0 = *(const short8v*)(bp);
            const short8v fb1 = *(const short8v*)(bp + 32);
            const short8v fb2 = *(const short8v*)(bp + 64);
            floatx4 a = {0.f, 0.f, 0.f, 0.f};
            a = __builtin_amdgcn_mfma_f32_16x16x32_bf16(wa_f[0], fb0, a, 0, 0, 0);
            a = __builtin_amdgcn_mfma_f32_16x16x32_bf16(wa_f[1], fb1, a, 0, 0, 0);
            a = __builtin_amdgcn_mfma_f32_16x16x32_bf16(wa_f[2], fb2, a, 0, 0, 0);
            accA[nt] = a;
            floatx4 y = {0.f, 0.f, 0.f, 0.f};
            y = __builtin_amdgcn_mfma_f32_16x16x32_bf16(w1_f[0], fb0, y, 0, 0, 0);
            y = __builtin_amdgcn_mfma_f32_16x16x32_bf16(w1_f[1], fb1, y, 0, 0, 0);
            y = __builtin_amdgcn_mfma_f32_16x16x32_bf16(w1_f[2], fb2, y, 0, 0, 0);
            short4v yp;
            yp[0] = f2bf(fmaxf(y[0] + b1v.x, 0.f));
            yp[1] = f2bf(fmaxf(y[1] + b1v.y, 0.f));
            yp[2] = f2bf(fmaxf(y[2] + b1v.z, 0.f));
            yp[3] = f2bf(fmaxf(y[3] + b1v.w, 0.f));
            *(short4v*)&s_y1[(nt * 16 + l15) * SY1 + crow] = yp;
        }
        __syncthreads();   // bar2: y1 ready; all s_fj reads of this iter done

        // ---- write prefetched gather for iter n+1 (safe: past bar2) ----
        if (pf) {
            uint4* dst = (uint4*)&s_fj[col * SFJ + h * 32];
            dst[0] = g0; dst[1] = g1; dst[2] = g2; dst[3] = g3;
            if (h) {
                short8v dp = {};
                dp[0] = f2bf(Pjn.x - Pnn.x);
                dp[1] = f2bf(Pjn.y - Pnn.y);
                dp[2] = f2bf(Pjn.z - Pnn.z);
                *(short8v*)&s_fj[col * SFJ + 64] = dp;
            }
        }

        // ---- fres: 4 aligned float4 loads; nb0 = within-batch index ----
        const int nb0 = pt0 & (N_ - 1);   // multiple of 4; nb0+3 <= 4095
        float4 f4r[4];
        #pragma unroll
        for (int r = 0; r < 4; ++r)
            f4r[r] = *(const float4*)&f[((size_t)(bb * 64 + crow + r)) * N_ + nb0];

        // ---- conv2 MFMAs interleaved with softmax, per point ----
        #pragma unroll
        for (int pi = 0; pi < PTS; ++pi) {
            floatx4 xx0, xx1;
            {
                const short* bp = &s_y1[((2 * pi) * 16 + l15) * SY1 + quad * 8];
                const short8v yb0 = *(const short8v*)(bp);
                const short8v yb1 = *(const short8v*)(bp + 32);
                floatx4 x = {0.f, 0.f, 0.f, 0.f};
                x = __builtin_amdgcn_mfma_f32_16x16x32_bf16(w2_f[0], yb0, x, 0, 0, 0);
                x = __builtin_amdgcn_mfma_f32_16x16x32_bf16(w2_f[1], yb1, x, 0, 0, 0);
                xx0 = x;
            }
            {
                const short* bp = &s_y1[((2 * pi + 1) * 16 + l15) * SY1 + quad * 8];
                const short8v yb0 = *(const short8v*)(bp);
                const short8v yb1 = *(const short8v*)(bp + 32);
                floatx4 x = {0.f, 0.f, 0.f, 0.f};
                x = __builtin_amdgcn_mfma_f32_16x16x32_bf16(w2_f[0], yb0, x, 0, 0, 0);
                x = __builtin_amdgcn_mfma_f32_16x16x32_bf16(w2_f[1], yb1, x, 0, 0, 0);
                xx1 = x;
            }
            float fo[4];
            #pragma unroll
            for (int r = 0; r < 4; ++r) {
                const float ba = (r == 0) ? bav.x : (r == 1) ? bav.y : (r == 2) ? bav.z : bav.w;
                const float bx = (r == 0) ? b2v.x : (r == 1) ? b2v.y : (r == 2) ? b2v.z : b2v.w;
                const float e0 = __expf(accA[2 * pi][r] + ba);
                const float e1 = __expf(accA[2 * pi + 1][r] + ba);
                const float t01 = e0 + e1;
                const float se = row16_sum(t01);
                const float sw = row16_sum(e0 * xx0[r] + e1 * xx1[r] + t01 * bx);
                const float fres = (pi == 0) ? f4r[r].x : (pi == 1) ? f4r[r].y
                                 : (pi == 2) ? f4r[r].z : f4r[r].w;
                fo[r] = fmaxf(sw * __builtin_amdgcn_rcpf(se) + fres, 0.f);
            }
            if (l15 == 0) {
                const int prow = itn * PTS + pi;        // point row 0..15
                *(float4*)&s_vec[prow * 64 + crow] = make_float4(fo[0], fo[1], fo[2], fo[3]);
                short4v fb;
                fb[0] = f2bf(fo[0]); fb[1] = f2bf(fo[1]);
                fb[2] = f2bf(fo[2]); fb[3] = f2bf(fo[3]);
                *(short4v*)&s_vecbf[prow * SFB + crow] = fb;
            }
        }
        __syncthreads();   // bar_end: publishes vecbf rows + s_fj gather;
                           // protects s_y1 from next iter's phase-A writes
    }

    // ---- BATCHED FFN layer 1: M=16 (wave ch), K=64 (ch), N=16 (points) ----
    {
        const short8v vb0 = *(const short8v*)&s_vecbf[l15 * SFB + quad * 8];
        const short8v vb1 = *(const short8v*)&s_vecbf[l15 * SFB + 32 + quad * 8];
        floatx4 d = {0.f, 0.f, 0.f, 0.f};
        d = __builtin_amdgcn_mfma_f32_16x16x32_bf16(wf1_f[0], vb0, d, 0, 0, 0);
        d = __builtin_amdgcn_mfma_f32_16x16x32_bf16(wf1_f[1], vb1, d, 0, 0, 0);
        short4v hb;
        hb[0] = f2bf(fmaxf(d[0] + bf1v.x, 0.f));
        hb[1] = f2bf(fmaxf(d[1] + bf1v.y, 0.f));
        hb[2] = f2bf(fmaxf(d[2] + bf1v.z, 0.f));
        hb[3] = f2bf(fmaxf(d[3] + bf1v.w, 0.f));
        *(short4v*)&s_hbf[l15 * SFB + crow] = hb;   // all 16 rows real
    }
    __syncthreads();   // h ready (cross-wave channels)

    // ---- BATCHED FFN layer 2 + residual + relu, store all 16 points ----
    {
        const short8v hb0 = *(const short8v*)&s_hbf[l15 * SFB + quad * 8];
        const short8v hb1 = *(const short8v*)&s_hbf[l15 * SFB + 32 + quad * 8];
        floatx4 d = {0.f, 0.f, 0.f, 0.f};
        d = __builtin_amdgcn_mfma_f32_16x16x32_bf16(wf2_f[0], hb0, d, 0, 0, 0);
        d = __builtin_amdgcn_mfma_f32_16x16x32_bf16(wf2_f[1], hb1, d, 0, 0, 0);
        const int n = (pt00 + l15) & (N_ - 1);       // block spans one batch
        out[((size_t)(bb * 64 + crow + 0)) * N_ + n] =
            fmaxf(d[0] + bf2v.x + s_vec[l15 * 64 + crow + 0], 0.f);
        out[((size_t)(bb * 64 + crow + 1)) * N_ + n] =
            fmaxf(d[1] + bf2v.y + s_vec[l15 * 64 + crow + 1], 0.f);
        out[((size_t)(bb * 64 + crow + 2)) * N_ + n] =
            fmaxf(d[2] + bf2v.z + s_vec[l15 * 64 + crow + 2], 0.f);
        out[((size_t)(bb * 64 + crow + 3)) * N_ + n] =
            fmaxf(d[3] + bf2v.w + s_vec[l15 * 64 + crow + 3], 0.f);
    }
    // hazard audit (batched): per iter, s_fj gather-writes (post-bar2(n)) vs
    // phase-A(n+1) reads separated by bar_end(n); s_y1 phase-A(n+1) writes vs
    // conv2(n) reads separated by bar_end(n); vecbf/s_vec rows written pre-
    // bar_end(n), read only after bar_end(3) (FFN1) / FFN-barrier (store) —
    // rows are per-(itn,pi) disjoint so no overwrite hazard; s_hbf written
    // once (FFN1), read after the FFN barrier.
}

extern "C" void kernel_launch(void* const* d_in, const int* in_sizes, int n_in,
                              void* d_out, int out_size, void* d_ws, size_t ws_size,
                              hipStream_t stream)
{
    const float* p      = (const float*)d_in[0];
    const float* f      = (const float*)d_in[1];
    const float* w_attn = (const float*)d_in[2];
    const float* b_attn = (const float*)d_in[3];
    const float* w1     = (const float*)d_in[4];
    const float* b1     = (const float*)d_in[5];
    const float* w2     = (const float*)d_in[6];
    const float* b2     = (const float*)d_in[7];
    const float* wf1    = (const float*)d_in[8];
    const float* bf1    = (const float*)d_in[9];
    const float* wf2    = (const float*)d_in[10];
    const float* bf2    = (const float*)d_in[11];
    float* out = (float*)d_out;

    unsigned short* idx = (unsigned short*)d_ws;                             // 2 MB
    unsigned short* ftb = (unsigned short*)((char*)d_ws + 2u * 1024 * 1024); // 4 MB
    float4* p4          = (float4*)((char*)d_ws + 6u * 1024 * 1024);         // 512 KB

    prep_kernel<<<B_ * (N_ / 64), 256, 0, stream>>>(p, f, ftb, p4, out);
    // 32768 queries / 4 per wave / 4 waves per block = 2048 blocks
    ball_query_kernel<<<(B_ * N_) / 16, 256, 0, stream>>>(p4, idx);
    lpa_mfma_kernel<<<(B_ * N_) / (PTS * ITERS), 256, 0, stream>>>(
        p4, f, ftb, w_attn, b_attn, w1, b1, w2, b2, wf1, bf1, wf2, bf2,
        idx, out + (size_t)B_ * N_ * 3);
}